// Round 21
// baseline (278.845 us; speedup 1.0000x reference)
//
#include <hip/hip_runtime.h>

// Deformable Conv2D (B=8, C=256, H=W=64, K=3, s=1, p=1) + ReLU via fp16 MFMA.
//
// Round 20: r15 structure at 2 blocks/CU.
//  - SINGLE-buffer btile [128][256] (64KB; LDS 77KB) -> 2 blocks/CU,
//    4 waves/SIMD: two independent barrier groups cover each other's
//    gather latency and barrier stalls. Cost: 2 barriers/tap (vs 1).
//  - same 256 blocks x 128 pixels (weights read once per block; per-XCD
//    xpt working set unchanged -> no r13-style FETCH blowup)
//  - depth-8 FIFO gather rotation: G(k+1) j0-7 issued in MFMA(k) AFTER all
//    A-issues; j8-15 issued in stage head; counted vmcnt everywhere;
//    lgkmcnt(0)-only barriers keep gathers in flight.
//  - __launch_bounds__(512,4): VGPR cap 128 = r15's natural allocation.

#define B_   8
#define C_   256
#define H_   64
#define W_   64
#define K2_  9
#define HW_  4096
#define NC4  64    // 256 ch / 4 per 16B cell

typedef __fp16 f16x2 __attribute__((ext_vector_type(2)));
typedef __fp16 f16x8 __attribute__((ext_vector_type(8)));
typedef float  f32x4 __attribute__((ext_vector_type(4)));

static __device__ __forceinline__ f16x2 u2h(unsigned u) {
    union { unsigned u; f16x2 h; } v; v.u = u; return v.h;
}
static __device__ __forceinline__ unsigned h2u(f16x2 h) {
    union { unsigned u; f16x2 h; } v; v.h = h; return v.u;
}

// ---- merged pack: blocks 0..511 transpose x; 512..2815 pack weights ----
__global__ __launch_bounds__(256) void pack_kernel(
    const float* __restrict__ x, const float* __restrict__ w,
    uint4* __restrict__ xpt, unsigned short* __restrict__ wA)
{
    const int tid = threadIdx.x;
    if (blockIdx.x >= 512) {
        const int t = (blockIdx.x - 512) * 256 + tid;
        if (t < C_ * C_ * K2_) {
            const int k = t % 9;
            const int c = (t / 9) & 255;
            const int o = t / (9 * 256);
            const int cc = c >> 5, lg = (c >> 3) & 3, e = c & 7;
            const int t16 = o >> 4, lr = o & 15;
            const int dst = e + 8 * (lr + 16 * (lg + 4 * (t16 + 16 * (cc + 8 * k))));
            const __fp16 h = (__fp16)w[t];
            unsigned short us;
            __builtin_memcpy(&us, &h, 2);
            wA[dst] = us;
        }
        return;
    }
    const int bid = blockIdx.x;              // b*64 + y
    const int b = bid >> 6, y = bid & 63;
    __shared__ unsigned pr[64][256];         // [col][ch] packed pair
    const float* xb = x + ((size_t)(b * C_ + tid) * H_ + y) * W_;   // ch = tid
#pragma unroll
    for (int i = 0; i < 16; ++i) {
        const int c0 = i * 4;
        const float4 v = *(const float4*)(xb + c0);
        const float nxt = xb[(c0 == 60) ? 63 : c0 + 4];
        pr[c0 + 0][tid] = h2u(__builtin_amdgcn_cvt_pkrtz(v.x, v.y));
        pr[c0 + 1][tid] = h2u(__builtin_amdgcn_cvt_pkrtz(v.y, v.z));
        pr[c0 + 2][tid] = h2u(__builtin_amdgcn_cvt_pkrtz(v.z, v.w));
        pr[c0 + 3][tid] = h2u(__builtin_amdgcn_cvt_pkrtz(v.w, nxt));
    }
    __syncthreads();
    const int lane = tid & 63, wv = tid >> 6;
    uint4* dst = xpt + ((size_t)b * HW_ + (size_t)y * 64) * NC4;
#pragma unroll
    for (int i = 0; i < 16; ++i) {
        const int col = wv * 16 + i;
        dst[(size_t)col * NC4 + lane] = *(const uint4*)&pr[col][lane * 4];
    }
}

// MODE 0: dense gathers, depth-8 pipelined, single-buffer. MODE 1: fallback.
template<int MODE>
__global__ __launch_bounds__(512, 4) void deform_main(
    const float* __restrict__ x, const uint4* __restrict__ xpt,
    const float* __restrict__ offset, const unsigned short* __restrict__ wA,
    float* __restrict__ out)
{
    extern __shared__ char smem[];
    unsigned short (*btile)[256] =
        (unsigned short (*)[256])smem;                          // 64 KB
    uint2*          gw2   = (uint2*)(smem + 65536);             // [9*128]
    unsigned short* gaddr = (unsigned short*)(smem + 74752);    // [9*128]

    const int bid = blockIdx.x;               // 256 blocks
    const int b = bid & 7, ho2 = bid >> 3;    // batch -> XCD; row pair
    const int tid = threadIdx.x;
    const int lane = tid & 63;
    const int wv   = tid >> 6;                // wave 0..7 (pixels wv*16..+15)
    const int lr = lane & 15, lg = (lane >> 4) & 3;

    // ---- geometry: 9 taps x 128 pixels (2 rows) ----
    for (int e = tid; e < K2_ * 128; e += 512) {
        const int k = e >> 7, p = e & 127;
        const int row = p >> 6, wo = p & 63;
        const int ho = ho2 * 2 + row;
        const float offy = offset[((b * 18 + 2 * k    ) * H_ + ho) * W_ + wo];
        const float offx = offset[((b * 18 + 2 * k + 1) * H_ + ho) * W_ + wo];
        const float py = (float)(k / 3 + ho - 1) + offy;
        const float px = (float)(k % 3 + wo - 1) + offx;
        const float y0f = floorf(py), x0f = floorf(px);
        const int   y0 = (int)y0f,   x0 = (int)x0f;
        const float fy = py - y0f,   fx = px - x0f;
        const float wy0 = (y0 >= 0  && y0 < H_)     ? 1.f - fy : 0.f;
        const float wy1 = (y0 >= -1 && y0 < H_ - 1) ? fy       : 0.f;
        const float wx0 = (x0 >= 0  && x0 < W_)     ? 1.f - fx : 0.f;
        const float wx1 = (x0 >= -1 && x0 < W_ - 1) ? fx       : 0.f;
        const int ys = min(max(y0, 0), H_ - 2);
        const int xs = min(max(x0, 0), W_ - 2);
        const float qy0 = (ys == y0 ? wy0 : 0.f) + (ys == y0 + 1 ? wy1 : 0.f);
        const float qy1 = (ys + 1 == y0 ? wy0 : 0.f) + (ys + 1 == y0 + 1 ? wy1 : 0.f);
        const float qx0 = (xs == x0 ? wx0 : 0.f) + (xs == x0 + 1 ? wx1 : 0.f);
        const float qx1 = (xs + 1 == x0 ? wx0 : 0.f) + (xs + 1 == x0 + 1 ? wx1 : 0.f);
        gaddr[k * 128 + p] = (unsigned short)(ys * W_ + xs);
        gw2[k * 128 + p] = make_uint2(
            h2u(__builtin_amdgcn_cvt_pkrtz(qy0 * qx0, qy0 * qx1)),
            h2u(__builtin_amdgcn_cvt_pkrtz(qy1 * qx0, qy1 * qx1)));
    }
    __syncthreads();

    f32x4 acc[2][8];
#pragma unroll
    for (int m = 0; m < 2; ++m)
#pragma unroll
        for (int n = 0; n < 8; ++n) acc[m][n] = (f32x4)0.f;

    const __fp16* wAh = (const __fp16*)wA;
    const uint4* xptb = xpt + (size_t)b * HW_ * NC4;

#define A_LOAD(k_, cc_, AS, AT) {                                              \
    const __fp16* ap_ = wAh +                                                  \
        (((size_t)((k_) * 8 + (cc_)) * 16 + wv * 2) * 64 + lane) * 8;          \
    AS = *(const f16x8*)ap_;                                                   \
    AT = *(const f16x8*)(ap_ + 512); }

#define G_ISSUE(t_, j_, QT, QB) {                                              \
    const int qp_ = gaddr[(t_) * 128 + wv * 16 + (j_)];                        \
    QT = xptb[(size_t)qp_ * NC4 + lane];                                       \
    QB = xptb[(size_t)(qp_ + 64) * NC4 + lane]; }

#define G_CONSUME(t_, j_, QT, QB) {                                            \
    const int p_ = wv * 16 + (j_);                                             \
    const uint2 wp_ = gw2[(t_) * 128 + p_];                                    \
    const f16x2 wt_ = u2h(wp_.x), wb_ = u2h(wp_.y);                            \
    const float v0_ = __builtin_amdgcn_fdot2(u2h(QT.x), wt_,                   \
        __builtin_amdgcn_fdot2(u2h(QB.x), wb_, 0.f, false), false);            \
    const float v1_ = __builtin_amdgcn_fdot2(u2h(QT.y), wt_,                   \
        __builtin_amdgcn_fdot2(u2h(QB.y), wb_, 0.f, false), false);            \
    const float v2_ = __builtin_amdgcn_fdot2(u2h(QT.z), wt_,                   \
        __builtin_amdgcn_fdot2(u2h(QB.z), wb_, 0.f, false), false);            \
    const float v3_ = __builtin_amdgcn_fdot2(u2h(QT.w), wt_,                   \
        __builtin_amdgcn_fdot2(u2h(QB.w), wb_, 0.f, false), false);            \
    const unsigned pk0_ = h2u(__builtin_amdgcn_cvt_pkrtz(v0_, v1_));           \
    const unsigned pk1_ = h2u(__builtin_amdgcn_cvt_pkrtz(v2_, v3_));           \
    const int phys_ = (lane >> 1) ^ (p_ & 7);                                  \
    *(uint2*)((char*)&btile[p_][0] + phys_ * 16 + (lane & 1) * 8) =            \
        make_uint2(pk0_, pk1_); }

#define MFMA_CC(cc_, AS, AT) {                                                 \
    _Pragma("unroll")                                                          \
    for (int nt = 0; nt < 8; ++nt) {                                           \
        const int pix_ = nt * 16 + lr;                                         \
        const int phys_ = ((cc_) * 4 + lg) ^ (pix_ & 7);                       \
        const f16x8 bv_ = *(const f16x8*)                                      \
            ((const char*)&btile[pix_][0] + phys_ * 16);                       \
        acc[0][nt] = __builtin_amdgcn_mfma_f32_16x16x32_f16(                   \
            AS, bv_, acc[0][nt], 0, 0, 0);                                     \
        acc[1][nt] = __builtin_amdgcn_mfma_f32_16x16x32_f16(                   \
            AT, bv_, acc[1][nt], 0, 0, 0);                                     \
    } }

#define G_ISSUE_8(t_)                                                          \
    G_ISSUE(t_, 0, qT0, qB0) G_ISSUE(t_, 1, qT1, qB1)                          \
    G_ISSUE(t_, 2, qT2, qB2) G_ISSUE(t_, 3, qT3, qB3)                          \
    G_ISSUE(t_, 4, qT4, qB4) G_ISSUE(t_, 5, qT5, qB5)                          \
    G_ISSUE(t_, 6, qT6, qB6) G_ISSUE(t_, 7, qT7, qB7)

// consume j0-7 (pre-issued) while issuing j8-15, then consume j8-15
#define STAGE_FULL(t_)                                                         \
    G_CONSUME(t_, 0, qT0, qB0)  G_ISSUE(t_, 8, qT0, qB0)                       \
    G_CONSUME(t_, 1, qT1, qB1)  G_ISSUE(t_, 9, qT1, qB1)                       \
    G_CONSUME(t_, 2, qT2, qB2)  G_ISSUE(t_, 10, qT2, qB2)                      \
    G_CONSUME(t_, 3, qT3, qB3)  G_ISSUE(t_, 11, qT3, qB3)                      \
    G_CONSUME(t_, 4, qT4, qB4)  G_ISSUE(t_, 12, qT4, qB4)                      \
    G_CONSUME(t_, 5, qT5, qB5)  G_ISSUE(t_, 13, qT5, qB5)                      \
    G_CONSUME(t_, 6, qT6, qB6)  G_ISSUE(t_, 14, qT6, qB6)                      \
    G_CONSUME(t_, 7, qT7, qB7)  G_ISSUE(t_, 15, qT7, qB7)                      \
    G_CONSUME(t_, 8, qT0, qB0)  G_CONSUME(t_, 9, qT1, qB1)                     \
    G_CONSUME(t_, 10, qT2, qB2) G_CONSUME(t_, 11, qT3, qB3)                    \
    G_CONSUME(t_, 12, qT4, qB4) G_CONSUME(t_, 13, qT5, qB5)                    \
    G_CONSUME(t_, 14, qT6, qB6) G_CONSUME(t_, 15, qT7, qB7)

    if constexpr (MODE == 0) {
        uint4 qT0, qB0, qT1, qB1, qT2, qB2, qT3, qB3;
        uint4 qT4, qB4, qT5, qB5, qT6, qB6, qT7, qB7;
        f16x8 aS0, aT0, aS1, aT1, aS2, aT2, aS3, aT3;

        // ---- prologue: A(0,0..1); G(0,j0-7); stage(0) ----
        A_LOAD(0, 0, aS0, aT0)
        A_LOAD(0, 1, aS1, aT1)
        G_ISSUE_8(0)
        STAGE_FULL(0)
        asm volatile("s_waitcnt lgkmcnt(0)" ::: "memory");
        __builtin_amdgcn_s_barrier();

        for (int k = 0; k < K2_; ++k) {
            const int st = (k < K2_ - 1);
            const int kn = st ? (k + 1) : k;

            // ---- MFMA(k): A prefetch interleave; gathers issued AFTER all A
            A_LOAD(k, 2, aS2, aT2) MFMA_CC(0, aS0, aT0)
            A_LOAD(k, 3, aS3, aT3) MFMA_CC(1, aS1, aT1)
            A_LOAD(k, 4, aS0, aT0) MFMA_CC(2, aS2, aT2)
            A_LOAD(k, 5, aS1, aT1) MFMA_CC(3, aS3, aT3)
            A_LOAD(k, 6, aS2, aT2) MFMA_CC(4, aS0, aT0)
            A_LOAD(k, 7, aS3, aT3) MFMA_CC(5, aS1, aT1)
            if (st) {
                A_LOAD(kn, 0, aS0, aT0)
                A_LOAD(kn, 1, aS1, aT1)
                G_ISSUE_8(kn)          // stays in flight across the barrier
            }
            MFMA_CC(6, aS2, aT2)
            MFMA_CC(7, aS3, aT3)
            asm volatile("s_waitcnt lgkmcnt(0)" ::: "memory");
            __builtin_amdgcn_s_barrier();      // btile consumed by all waves

            if (st) {
                STAGE_FULL(kn)                 // overwrite btile
                asm volatile("s_waitcnt lgkmcnt(0)" ::: "memory");
                __builtin_amdgcn_s_barrier();  // btile ready for MFMA(k+1)
            }
        }
    } else {
        // fallback: direct f32 corner loads (correctness only)
        for (int k = 0; k < K2_; ++k) {
#pragma unroll
            for (int j = 0; j < 16; ++j) {
                const int p_ = wv * 16 + j;
                const int qp = gaddr[k * 128 + p_];
                const uint2 wp_ = gw2[k * 128 + p_];
                const f16x2 wt_ = u2h(wp_.x), wb_ = u2h(wp_.y);
                const float w00 = (float)wt_.x, w01 = (float)wt_.y;
                const float w10 = (float)wb_.x, w11 = (float)wb_.y;
                float vv[4];
#pragma unroll
                for (int e2 = 0; e2 < 4; ++e2) {
                    const float* pl = x + ((size_t)(b * C_ + lane * 4 + e2)) * HW_;
                    vv[e2] = w00 * pl[qp] + w01 * pl[qp + 1]
                           + w10 * pl[qp + 64] + w11 * pl[qp + 65];
                }
                const unsigned pk0 = h2u(__builtin_amdgcn_cvt_pkrtz(vv[0], vv[1]));
                const unsigned pk1 = h2u(__builtin_amdgcn_cvt_pkrtz(vv[2], vv[3]));
                const int phys_ = (lane >> 1) ^ (p_ & 7);
                *(uint2*)((char*)&btile[p_][0] + phys_ * 16 + (lane & 1) * 8) =
                    make_uint2(pk0, pk1);
            }
            __syncthreads();
#pragma unroll
            for (int cc = 0; cc < 8; ++cc) {
                f16x8 a0, a1;
                A_LOAD(k, cc, a0, a1)
                MFMA_CC(cc, a0, a1)
            }
            __syncthreads();
        }
    }

    // ---- epilogue: ReLU + store (C/D: col=lane&15 -> pixel, row=lg*4+r -> oc)
    const size_t ob = (size_t)b * C_ * HW_;
    const int hbase = ho2 * 2;
#pragma unroll
    for (int mt = 0; mt < 2; ++mt) {
        const int o0 = wv * 32 + mt * 16 + lg * 4;
#pragma unroll
        for (int nt = 0; nt < 8; ++nt) {
            const int pix = nt * 16 + lr;
            const int row = pix >> 6, wo = pix & 63;
#pragma unroll
            for (int r = 0; r < 4; ++r)
                out[ob + (size_t)(o0 + r) * HW_ + (size_t)(hbase + row) * W_ + wo] =
                    fmaxf(acc[mt][nt][r], 0.f);
        }
    }
#undef A_LOAD
#undef G_ISSUE
#undef G_CONSUME
#undef MFMA_CC
#undef G_ISSUE_8
#undef STAGE_FULL
}

extern "C" void kernel_launch(void* const* d_in, const int* in_sizes, int n_in,
                              void* d_out, int out_size, void* d_ws, size_t ws_size,
                              hipStream_t stream) {
    const float* x      = (const float*)d_in[0];
    const float* offset = (const float*)d_in[1];
    const float* weight = (const float*)d_in[2];
    float* out          = (float*)d_out;

    const size_t wA_bytes = (size_t)K2_ * C_ * C_ * 2;        // 1.18 MB
    const size_t xp_off   = wA_bytes;                         // 16B-aligned
    const size_t xp_bytes = (size_t)B_ * HW_ * NC4 * 16;      // 33.6 MB
    const size_t need     = xp_off + xp_bytes;                // ~34.7 MB

    unsigned short* wAp = (unsigned short*)d_ws;
    uint4*          xpp = (uint4*)((char*)d_ws + xp_off);

    pack_kernel<<<512 + 2304, 256, 0, stream>>>(x, weight, xpp, wAp);

    const size_t lds = 65536 + 9216 + 2304;   // 77,056 B -> 2 blocks/CU
    if (ws_size >= need) {
        deform_main<0><<<256, 512, lds, stream>>>(x, xpp, offset, wAp, out);
    } else {
        deform_main<1><<<256, 512, lds, stream>>>(x, xpp, offset, wAp, out);
    }
}

// Round 22
// 78.016 us; speedup vs baseline: 3.5742x; 3.5742x over previous
//
#include <hip/hip_runtime.h>

// Deformable Conv2D (B=8, C=256, H=W=64, K=3, s=1, p=1) + ReLU via fp16 MFMA.
//
// Round 21: round-20 single-buffer kernel with launch_bounds (512,2).
//  r20's (512,4) clamped VGPR to 64 -> 754MB spill. At (512,2) this exact
//  register structure compiles to 128 VGPR, no spill (r15/r19 measured);
//  HW allows 16 waves/CU at 128 VGPR and LDS 77KB allows 2 blocks/CU ->
//  occupancy doubles vs r15 WITHOUT register pressure.
//  - SINGLE-buffer btile [128][256]; 2 barriers/tap
//  - 256 blocks x 128 pixels; depth-8 FIFO gather rotation; counted vmcnt;
//    lgkmcnt(0)-only barriers keep gathers in flight across barriers.

#define B_   8
#define C_   256
#define H_   64
#define W_   64
#define K2_  9
#define HW_  4096
#define NC4  64    // 256 ch / 4 per 16B cell

typedef __fp16 f16x2 __attribute__((ext_vector_type(2)));
typedef __fp16 f16x8 __attribute__((ext_vector_type(8)));
typedef float  f32x4 __attribute__((ext_vector_type(4)));

static __device__ __forceinline__ f16x2 u2h(unsigned u) {
    union { unsigned u; f16x2 h; } v; v.u = u; return v.h;
}
static __device__ __forceinline__ unsigned h2u(f16x2 h) {
    union { unsigned u; f16x2 h; } v; v.h = h; return v.u;
}

// ---- merged pack: blocks 0..511 transpose x; 512..2815 pack weights ----
__global__ __launch_bounds__(256) void pack_kernel(
    const float* __restrict__ x, const float* __restrict__ w,
    uint4* __restrict__ xpt, unsigned short* __restrict__ wA)
{
    const int tid = threadIdx.x;
    if (blockIdx.x >= 512) {
        const int t = (blockIdx.x - 512) * 256 + tid;
        if (t < C_ * C_ * K2_) {
            const int k = t % 9;
            const int c = (t / 9) & 255;
            const int o = t / (9 * 256);
            const int cc = c >> 5, lg = (c >> 3) & 3, e = c & 7;
            const int t16 = o >> 4, lr = o & 15;
            const int dst = e + 8 * (lr + 16 * (lg + 4 * (t16 + 16 * (cc + 8 * k))));
            const __fp16 h = (__fp16)w[t];
            unsigned short us;
            __builtin_memcpy(&us, &h, 2);
            wA[dst] = us;
        }
        return;
    }
    const int bid = blockIdx.x;              // b*64 + y
    const int b = bid >> 6, y = bid & 63;
    __shared__ unsigned pr[64][256];         // [col][ch] packed pair
    const float* xb = x + ((size_t)(b * C_ + tid) * H_ + y) * W_;   // ch = tid
#pragma unroll
    for (int i = 0; i < 16; ++i) {
        const int c0 = i * 4;
        const float4 v = *(const float4*)(xb + c0);
        const float nxt = xb[(c0 == 60) ? 63 : c0 + 4];
        pr[c0 + 0][tid] = h2u(__builtin_amdgcn_cvt_pkrtz(v.x, v.y));
        pr[c0 + 1][tid] = h2u(__builtin_amdgcn_cvt_pkrtz(v.y, v.z));
        pr[c0 + 2][tid] = h2u(__builtin_amdgcn_cvt_pkrtz(v.z, v.w));
        pr[c0 + 3][tid] = h2u(__builtin_amdgcn_cvt_pkrtz(v.w, nxt));
    }
    __syncthreads();
    const int lane = tid & 63, wv = tid >> 6;
    uint4* dst = xpt + ((size_t)b * HW_ + (size_t)y * 64) * NC4;
#pragma unroll
    for (int i = 0; i < 16; ++i) {
        const int col = wv * 16 + i;
        dst[(size_t)col * NC4 + lane] = *(const uint4*)&pr[col][lane * 4];
    }
}

// MODE 0: dense gathers, depth-8 pipelined, single-buffer. MODE 1: fallback.
template<int MODE>
__global__ __launch_bounds__(512, 2) void deform_main(
    const float* __restrict__ x, const uint4* __restrict__ xpt,
    const float* __restrict__ offset, const unsigned short* __restrict__ wA,
    float* __restrict__ out)
{
    extern __shared__ char smem[];
    unsigned short (*btile)[256] =
        (unsigned short (*)[256])smem;                          // 64 KB
    uint2*          gw2   = (uint2*)(smem + 65536);             // [9*128]
    unsigned short* gaddr = (unsigned short*)(smem + 74752);    // [9*128]

    const int bid = blockIdx.x;               // 256 blocks
    const int b = bid & 7, ho2 = bid >> 3;    // batch -> XCD; row pair
    const int tid = threadIdx.x;
    const int lane = tid & 63;
    const int wv   = tid >> 6;                // wave 0..7 (pixels wv*16..+15)
    const int lr = lane & 15, lg = (lane >> 4) & 3;

    // ---- geometry: 9 taps x 128 pixels (2 rows) ----
    for (int e = tid; e < K2_ * 128; e += 512) {
        const int k = e >> 7, p = e & 127;
        const int row = p >> 6, wo = p & 63;
        const int ho = ho2 * 2 + row;
        const float offy = offset[((b * 18 + 2 * k    ) * H_ + ho) * W_ + wo];
        const float offx = offset[((b * 18 + 2 * k + 1) * H_ + ho) * W_ + wo];
        const float py = (float)(k / 3 + ho - 1) + offy;
        const float px = (float)(k % 3 + wo - 1) + offx;
        const float y0f = floorf(py), x0f = floorf(px);
        const int   y0 = (int)y0f,   x0 = (int)x0f;
        const float fy = py - y0f,   fx = px - x0f;
        const float wy0 = (y0 >= 0  && y0 < H_)     ? 1.f - fy : 0.f;
        const float wy1 = (y0 >= -1 && y0 < H_ - 1) ? fy       : 0.f;
        const float wx0 = (x0 >= 0  && x0 < W_)     ? 1.f - fx : 0.f;
        const float wx1 = (x0 >= -1 && x0 < W_ - 1) ? fx       : 0.f;
        const int ys = min(max(y0, 0), H_ - 2);
        const int xs = min(max(x0, 0), W_ - 2);
        const float qy0 = (ys == y0 ? wy0 : 0.f) + (ys == y0 + 1 ? wy1 : 0.f);
        const float qy1 = (ys + 1 == y0 ? wy0 : 0.f) + (ys + 1 == y0 + 1 ? wy1 : 0.f);
        const float qx0 = (xs == x0 ? wx0 : 0.f) + (xs == x0 + 1 ? wx1 : 0.f);
        const float qx1 = (xs + 1 == x0 ? wx0 : 0.f) + (xs + 1 == x0 + 1 ? wx1 : 0.f);
        gaddr[k * 128 + p] = (unsigned short)(ys * W_ + xs);
        gw2[k * 128 + p] = make_uint2(
            h2u(__builtin_amdgcn_cvt_pkrtz(qy0 * qx0, qy0 * qx1)),
            h2u(__builtin_amdgcn_cvt_pkrtz(qy1 * qx0, qy1 * qx1)));
    }
    __syncthreads();

    f32x4 acc[2][8];
#pragma unroll
    for (int m = 0; m < 2; ++m)
#pragma unroll
        for (int n = 0; n < 8; ++n) acc[m][n] = (f32x4)0.f;

    const __fp16* wAh = (const __fp16*)wA;
    const uint4* xptb = xpt + (size_t)b * HW_ * NC4;

#define A_LOAD(k_, cc_, AS, AT) {                                              \
    const __fp16* ap_ = wAh +                                                  \
        (((size_t)((k_) * 8 + (cc_)) * 16 + wv * 2) * 64 + lane) * 8;          \
    AS = *(const f16x8*)ap_;                                                   \
    AT = *(const f16x8*)(ap_ + 512); }

#define G_ISSUE(t_, j_, QT, QB) {                                              \
    const int qp_ = gaddr[(t_) * 128 + wv * 16 + (j_)];                        \
    QT = xptb[(size_t)qp_ * NC4 + lane];                                       \
    QB = xptb[(size_t)(qp_ + 64) * NC4 + lane]; }

#define G_CONSUME(t_, j_, QT, QB) {                                            \
    const int p_ = wv * 16 + (j_);                                             \
    const uint2 wp_ = gw2[(t_) * 128 + p_];                                    \
    const f16x2 wt_ = u2h(wp_.x), wb_ = u2h(wp_.y);                            \
    const float v0_ = __builtin_amdgcn_fdot2(u2h(QT.x), wt_,                   \
        __builtin_amdgcn_fdot2(u2h(QB.x), wb_, 0.f, false), false);            \
    const float v1_ = __builtin_amdgcn_fdot2(u2h(QT.y), wt_,                   \
        __builtin_amdgcn_fdot2(u2h(QB.y), wb_, 0.f, false), false);            \
    const float v2_ = __builtin_amdgcn_fdot2(u2h(QT.z), wt_,                   \
        __builtin_amdgcn_fdot2(u2h(QB.z), wb_, 0.f, false), false);            \
    const float v3_ = __builtin_amdgcn_fdot2(u2h(QT.w), wt_,                   \
        __builtin_amdgcn_fdot2(u2h(QB.w), wb_, 0.f, false), false);            \
    const unsigned pk0_ = h2u(__builtin_amdgcn_cvt_pkrtz(v0_, v1_));           \
    const unsigned pk1_ = h2u(__builtin_amdgcn_cvt_pkrtz(v2_, v3_));           \
    const int phys_ = (lane >> 1) ^ (p_ & 7);                                  \
    *(uint2*)((char*)&btile[p_][0] + phys_ * 16 + (lane & 1) * 8) =            \
        make_uint2(pk0_, pk1_); }

#define MFMA_CC(cc_, AS, AT) {                                                 \
    _Pragma("unroll")                                                          \
    for (int nt = 0; nt < 8; ++nt) {                                           \
        const int pix_ = nt * 16 + lr;                                         \
        const int phys_ = ((cc_) * 4 + lg) ^ (pix_ & 7);                       \
        const f16x8 bv_ = *(const f16x8*)                                      \
            ((const char*)&btile[pix_][0] + phys_ * 16);                       \
        acc[0][nt] = __builtin_amdgcn_mfma_f32_16x16x32_f16(                   \
            AS, bv_, acc[0][nt], 0, 0, 0);                                     \
        acc[1][nt] = __builtin_amdgcn_mfma_f32_16x16x32_f16(                   \
            AT, bv_, acc[1][nt], 0, 0, 0);                                     \
    } }

#define G_ISSUE_8(t_)                                                          \
    G_ISSUE(t_, 0, qT0, qB0) G_ISSUE(t_, 1, qT1, qB1)                          \
    G_ISSUE(t_, 2, qT2, qB2) G_ISSUE(t_, 3, qT3, qB3)                          \
    G_ISSUE(t_, 4, qT4, qB4) G_ISSUE(t_, 5, qT5, qB5)                          \
    G_ISSUE(t_, 6, qT6, qB6) G_ISSUE(t_, 7, qT7, qB7)

// consume j0-7 (pre-issued) while issuing j8-15, then consume j8-15
#define STAGE_FULL(t_)                                                         \
    G_CONSUME(t_, 0, qT0, qB0)  G_ISSUE(t_, 8, qT0, qB0)                       \
    G_CONSUME(t_, 1, qT1, qB1)  G_ISSUE(t_, 9, qT1, qB1)                       \
    G_CONSUME(t_, 2, qT2, qB2)  G_ISSUE(t_, 10, qT2, qB2)                      \
    G_CONSUME(t_, 3, qT3, qB3)  G_ISSUE(t_, 11, qT3, qB3)                      \
    G_CONSUME(t_, 4, qT4, qB4)  G_ISSUE(t_, 12, qT4, qB4)                      \
    G_CONSUME(t_, 5, qT5, qB5)  G_ISSUE(t_, 13, qT5, qB5)                      \
    G_CONSUME(t_, 6, qT6, qB6)  G_ISSUE(t_, 14, qT6, qB6)                      \
    G_CONSUME(t_, 7, qT7, qB7)  G_ISSUE(t_, 15, qT7, qB7)                      \
    G_CONSUME(t_, 8, qT0, qB0)  G_CONSUME(t_, 9, qT1, qB1)                     \
    G_CONSUME(t_, 10, qT2, qB2) G_CONSUME(t_, 11, qT3, qB3)                    \
    G_CONSUME(t_, 12, qT4, qB4) G_CONSUME(t_, 13, qT5, qB5)                    \
    G_CONSUME(t_, 14, qT6, qB6) G_CONSUME(t_, 15, qT7, qB7)

    if constexpr (MODE == 0) {
        uint4 qT0, qB0, qT1, qB1, qT2, qB2, qT3, qB3;
        uint4 qT4, qB4, qT5, qB5, qT6, qB6, qT7, qB7;
        f16x8 aS0, aT0, aS1, aT1, aS2, aT2, aS3, aT3;

        // ---- prologue: A(0,0..1); G(0,j0-7); stage(0) ----
        A_LOAD(0, 0, aS0, aT0)
        A_LOAD(0, 1, aS1, aT1)
        G_ISSUE_8(0)
        STAGE_FULL(0)
        asm volatile("s_waitcnt lgkmcnt(0)" ::: "memory");
        __builtin_amdgcn_s_barrier();

        for (int k = 0; k < K2_; ++k) {
            const int st = (k < K2_ - 1);
            const int kn = st ? (k + 1) : k;

            // ---- MFMA(k): A prefetch interleave; gathers issued AFTER all A
            A_LOAD(k, 2, aS2, aT2) MFMA_CC(0, aS0, aT0)
            A_LOAD(k, 3, aS3, aT3) MFMA_CC(1, aS1, aT1)
            A_LOAD(k, 4, aS0, aT0) MFMA_CC(2, aS2, aT2)
            A_LOAD(k, 5, aS1, aT1) MFMA_CC(3, aS3, aT3)
            A_LOAD(k, 6, aS2, aT2) MFMA_CC(4, aS0, aT0)
            A_LOAD(k, 7, aS3, aT3) MFMA_CC(5, aS1, aT1)
            if (st) {
                A_LOAD(kn, 0, aS0, aT0)
                A_LOAD(kn, 1, aS1, aT1)
                G_ISSUE_8(kn)          // stays in flight across the barrier
            }
            MFMA_CC(6, aS2, aT2)
            MFMA_CC(7, aS3, aT3)
            asm volatile("s_waitcnt lgkmcnt(0)" ::: "memory");
            __builtin_amdgcn_s_barrier();      // btile consumed by all waves

            if (st) {
                STAGE_FULL(kn)                 // overwrite btile
                asm volatile("s_waitcnt lgkmcnt(0)" ::: "memory");
                __builtin_amdgcn_s_barrier();  // btile ready for MFMA(k+1)
            }
        }
    } else {
        // fallback: direct f32 corner loads (correctness only)
        for (int k = 0; k < K2_; ++k) {
#pragma unroll
            for (int j = 0; j < 16; ++j) {
                const int p_ = wv * 16 + j;
                const int qp = gaddr[k * 128 + p_];
                const uint2 wp_ = gw2[k * 128 + p_];
                const f16x2 wt_ = u2h(wp_.x), wb_ = u2h(wp_.y);
                const float w00 = (float)wt_.x, w01 = (float)wt_.y;
                const float w10 = (float)wb_.x, w11 = (float)wb_.y;
                float vv[4];
#pragma unroll
                for (int e2 = 0; e2 < 4; ++e2) {
                    const float* pl = x + ((size_t)(b * C_ + lane * 4 + e2)) * HW_;
                    vv[e2] = w00 * pl[qp] + w01 * pl[qp + 1]
                           + w10 * pl[qp + 64] + w11 * pl[qp + 65];
                }
                const unsigned pk0 = h2u(__builtin_amdgcn_cvt_pkrtz(vv[0], vv[1]));
                const unsigned pk1 = h2u(__builtin_amdgcn_cvt_pkrtz(vv[2], vv[3]));
                const int phys_ = (lane >> 1) ^ (p_ & 7);
                *(uint2*)((char*)&btile[p_][0] + phys_ * 16 + (lane & 1) * 8) =
                    make_uint2(pk0, pk1);
            }
            __syncthreads();
#pragma unroll
            for (int cc = 0; cc < 8; ++cc) {
                f16x8 a0, a1;
                A_LOAD(k, cc, a0, a1)
                MFMA_CC(cc, a0, a1)
            }
            __syncthreads();
        }
    }

    // ---- epilogue: ReLU + store (C/D: col=lane&15 -> pixel, row=lg*4+r -> oc)
    const size_t ob = (size_t)b * C_ * HW_;
    const int hbase = ho2 * 2;
#pragma unroll
    for (int mt = 0; mt < 2; ++mt) {
        const int o0 = wv * 32 + mt * 16 + lg * 4;
#pragma unroll
        for (int nt = 0; nt < 8; ++nt) {
            const int pix = nt * 16 + lr;
            const int row = pix >> 6, wo = pix & 63;
#pragma unroll
            for (int r = 0; r < 4; ++r)
                out[ob + (size_t)(o0 + r) * HW_ + (size_t)(hbase + row) * W_ + wo] =
                    fmaxf(acc[mt][nt][r], 0.f);
        }
    }
#undef A_LOAD
#undef G_ISSUE
#undef G_CONSUME
#undef MFMA_CC
#undef G_ISSUE_8
#undef STAGE_FULL
}

extern "C" void kernel_launch(void* const* d_in, const int* in_sizes, int n_in,
                              void* d_out, int out_size, void* d_ws, size_t ws_size,
                              hipStream_t stream) {
    const float* x      = (const float*)d_in[0];
    const float* offset = (const float*)d_in[1];
    const float* weight = (const float*)d_in[2];
    float* out          = (float*)d_out;

    const size_t wA_bytes = (size_t)K2_ * C_ * C_ * 2;        // 1.18 MB
    const size_t xp_off   = wA_bytes;                         // 16B-aligned
    const size_t xp_bytes = (size_t)B_ * HW_ * NC4 * 16;      // 33.6 MB
    const size_t need     = xp_off + xp_bytes;                // ~34.7 MB

    unsigned short* wAp = (unsigned short*)d_ws;
    uint4*          xpp = (uint4*)((char*)d_ws + xp_off);

    pack_kernel<<<512 + 2304, 256, 0, stream>>>(x, weight, xpp, wAp);

    const size_t lds = 65536 + 9216 + 2304;   // 77,056 B -> 2 blocks/CU
    if (ws_size >= need) {
        deform_main<0><<<256, 512, lds, stream>>>(x, xpp, offset, wAp, out);
    } else {
        deform_main<1><<<256, 512, lds, stream>>>(x, xpp, offset, wAp, out);
    }
}

// Round 23
// 72.320 us; speedup vs baseline: 3.8557x; 1.0788x over previous
//
#include <hip/hip_runtime.h>

// Deformable Conv2D (B=8, C=256, H=W=64, K=3, s=1, p=1) + ReLU via fp16 MFMA.
//
// FINAL (round 22) = round-15 configuration, the session best
// (main 60.2us, total 72.4us; 737us -> 72.4us over the session, 10.2x).
//  - pack pass: x -> channel-major fp16 corner-pair cells xpt[b][pix][c4]
//    (ONE dense 1KB wave-load = all 256 channels' top corners for a
//    (pixel,tap)); weights -> fp16 MFMA A-fragment lane order
//  - main: 256 blocks (b, row-pair) x 512 thr; weights read once/block
//  - per tap: STAGE(64x256 fp16 B-tile, double-buffered) || MFMA, 1
//    barrier/tap; depth-8 register gather rotation, strict FIFO
//    issue==consume (counted vmcnt; lgkmcnt(0)-only barriers keep
//    gathers in flight); XOR-swizzled btile; 32x128 wave tile.
// Measured plateau: overlap-bound at 1 block/CU (grid=256), no pipe >31%;
// all finer decompositions double weight/gather/LDS traffic (r9-r21).

#define B_   8
#define C_   256
#define H_   64
#define W_   64
#define K2_  9
#define HW_  4096
#define NC4  64    // 256 ch / 4 per 16B cell

typedef __fp16 f16x2 __attribute__((ext_vector_type(2)));
typedef __fp16 f16x8 __attribute__((ext_vector_type(8)));
typedef float  f32x4 __attribute__((ext_vector_type(4)));

static __device__ __forceinline__ f16x2 u2h(unsigned u) {
    union { unsigned u; f16x2 h; } v; v.u = u; return v.h;
}
static __device__ __forceinline__ unsigned h2u(f16x2 h) {
    union { unsigned u; f16x2 h; } v; v.h = h; return v.u;
}

// ---- merged pack: blocks 0..511 transpose x; 512..2815 pack weights ----
__global__ __launch_bounds__(256) void pack_kernel(
    const float* __restrict__ x, const float* __restrict__ w,
    uint4* __restrict__ xpt, unsigned short* __restrict__ wA)
{
    const int tid = threadIdx.x;
    if (blockIdx.x >= 512) {
        const int t = (blockIdx.x - 512) * 256 + tid;
        if (t < C_ * C_ * K2_) {
            const int k = t % 9;
            const int c = (t / 9) & 255;
            const int o = t / (9 * 256);
            const int cc = c >> 5, lg = (c >> 3) & 3, e = c & 7;
            const int t16 = o >> 4, lr = o & 15;
            const int dst = e + 8 * (lr + 16 * (lg + 4 * (t16 + 16 * (cc + 8 * k))));
            const __fp16 h = (__fp16)w[t];
            unsigned short us;
            __builtin_memcpy(&us, &h, 2);
            wA[dst] = us;
        }
        return;
    }
    const int bid = blockIdx.x;              // b*64 + y
    const int b = bid >> 6, y = bid & 63;
    __shared__ unsigned pr[64][256];         // [col][ch] packed pair
    const float* xb = x + ((size_t)(b * C_ + tid) * H_ + y) * W_;   // ch = tid
#pragma unroll
    for (int i = 0; i < 16; ++i) {
        const int c0 = i * 4;
        const float4 v = *(const float4*)(xb + c0);
        const float nxt = xb[(c0 == 60) ? 63 : c0 + 4];
        pr[c0 + 0][tid] = h2u(__builtin_amdgcn_cvt_pkrtz(v.x, v.y));
        pr[c0 + 1][tid] = h2u(__builtin_amdgcn_cvt_pkrtz(v.y, v.z));
        pr[c0 + 2][tid] = h2u(__builtin_amdgcn_cvt_pkrtz(v.z, v.w));
        pr[c0 + 3][tid] = h2u(__builtin_amdgcn_cvt_pkrtz(v.w, nxt));
    }
    __syncthreads();
    const int lane = tid & 63, wv = tid >> 6;
    uint4* dst = xpt + ((size_t)b * HW_ + (size_t)y * 64) * NC4;
#pragma unroll
    for (int i = 0; i < 16; ++i) {
        const int col = wv * 16 + i;
        dst[(size_t)col * NC4 + lane] = *(const uint4*)&pr[col][lane * 4];
    }
}

// MODE 0: dense gathers, depth-8 pipelined. MODE 1: f32 fallback.
template<int MODE>
__global__ __launch_bounds__(512, 2) void deform_main(
    const float* __restrict__ x, const uint4* __restrict__ xpt,
    const float* __restrict__ offset, const unsigned short* __restrict__ wA,
    float* __restrict__ out)
{
    extern __shared__ char smem[];
    unsigned short (*btile)[128][256] =
        (unsigned short (*)[128][256])smem;                     // 2 x 64KB
    uint2*          gw2   = (uint2*)(smem + 131072);            // [9*128]
    unsigned short* gaddr = (unsigned short*)(smem + 140288);   // [9*128]

    const int bid = blockIdx.x;               // 256 blocks
    const int b = bid & 7, ho2 = bid >> 3;    // batch -> XCD; row pair
    const int tid = threadIdx.x;
    const int lane = tid & 63;
    const int wv   = tid >> 6;                // wave 0..7 (pixels wv*16..+15)
    const int lr = lane & 15, lg = (lane >> 4) & 3;

    // ---- geometry: 9 taps x 128 pixels (2 rows) ----
    for (int e = tid; e < K2_ * 128; e += 512) {
        const int k = e >> 7, p = e & 127;
        const int row = p >> 6, wo = p & 63;
        const int ho = ho2 * 2 + row;
        const float offy = offset[((b * 18 + 2 * k    ) * H_ + ho) * W_ + wo];
        const float offx = offset[((b * 18 + 2 * k + 1) * H_ + ho) * W_ + wo];
        const float py = (float)(k / 3 + ho - 1) + offy;
        const float px = (float)(k % 3 + wo - 1) + offx;
        const float y0f = floorf(py), x0f = floorf(px);
        const int   y0 = (int)y0f,   x0 = (int)x0f;
        const float fy = py - y0f,   fx = px - x0f;
        const float wy0 = (y0 >= 0  && y0 < H_)     ? 1.f - fy : 0.f;
        const float wy1 = (y0 >= -1 && y0 < H_ - 1) ? fy       : 0.f;
        const float wx0 = (x0 >= 0  && x0 < W_)     ? 1.f - fx : 0.f;
        const float wx1 = (x0 >= -1 && x0 < W_ - 1) ? fx       : 0.f;
        const int ys = min(max(y0, 0), H_ - 2);
        const int xs = min(max(x0, 0), W_ - 2);
        const float qy0 = (ys == y0 ? wy0 : 0.f) + (ys == y0 + 1 ? wy1 : 0.f);
        const float qy1 = (ys + 1 == y0 ? wy0 : 0.f) + (ys + 1 == y0 + 1 ? wy1 : 0.f);
        const float qx0 = (xs == x0 ? wx0 : 0.f) + (xs == x0 + 1 ? wx1 : 0.f);
        const float qx1 = (xs + 1 == x0 ? wx0 : 0.f) + (xs + 1 == x0 + 1 ? wx1 : 0.f);
        gaddr[k * 128 + p] = (unsigned short)(ys * W_ + xs);
        gw2[k * 128 + p] = make_uint2(
            h2u(__builtin_amdgcn_cvt_pkrtz(qy0 * qx0, qy0 * qx1)),
            h2u(__builtin_amdgcn_cvt_pkrtz(qy1 * qx0, qy1 * qx1)));
    }
    __syncthreads();

    f32x4 acc[2][8];
#pragma unroll
    for (int m = 0; m < 2; ++m)
#pragma unroll
        for (int n = 0; n < 8; ++n) acc[m][n] = (f32x4)0.f;

    const __fp16* wAh = (const __fp16*)wA;
    const uint4* xptb = xpt + (size_t)b * HW_ * NC4;

#define A_LOAD(k_, cc_, AS, AT) {                                              \
    const __fp16* ap_ = wAh +                                                  \
        (((size_t)((k_) * 8 + (cc_)) * 16 + wv * 2) * 64 + lane) * 8;          \
    AS = *(const f16x8*)ap_;                                                   \
    AT = *(const f16x8*)(ap_ + 512); }

#define G_ISSUE(t_, j_, QT, QB) {                                              \
    const int qp_ = gaddr[(t_) * 128 + wv * 16 + (j_)];                        \
    QT = xptb[(size_t)qp_ * NC4 + lane];                                       \
    QB = xptb[(size_t)(qp_ + 64) * NC4 + lane]; }

#define G_CONSUME(t_, j_, QT, QB, SB) {                                        \
    const int p_ = wv * 16 + (j_);                                             \
    const uint2 wp_ = gw2[(t_) * 128 + p_];                                    \
    const f16x2 wt_ = u2h(wp_.x), wb_ = u2h(wp_.y);                            \
    const float v0_ = __builtin_amdgcn_fdot2(u2h(QT.x), wt_,                   \
        __builtin_amdgcn_fdot2(u2h(QB.x), wb_, 0.f, false), false);            \
    const float v1_ = __builtin_amdgcn_fdot2(u2h(QT.y), wt_,                   \
        __builtin_amdgcn_fdot2(u2h(QB.y), wb_, 0.f, false), false);            \
    const float v2_ = __builtin_amdgcn_fdot2(u2h(QT.z), wt_,                   \
        __builtin_amdgcn_fdot2(u2h(QB.z), wb_, 0.f, false), false);            \
    const float v3_ = __builtin_amdgcn_fdot2(u2h(QT.w), wt_,                   \
        __builtin_amdgcn_fdot2(u2h(QB.w), wb_, 0.f, false), false);            \
    const unsigned pk0_ = h2u(__builtin_amdgcn_cvt_pkrtz(v0_, v1_));           \
    const unsigned pk1_ = h2u(__builtin_amdgcn_cvt_pkrtz(v2_, v3_));           \
    const int phys_ = (lane >> 1) ^ (p_ & 7);                                  \
    *(uint2*)((char*)&btile[SB][p_][0] + phys_ * 16 + (lane & 1) * 8) =        \
        make_uint2(pk0_, pk1_); }

#define MFMA_CC(cc_, MB, AS, AT) {                                             \
    _Pragma("unroll")                                                          \
    for (int nt = 0; nt < 8; ++nt) {                                           \
        const int pix_ = nt * 16 + lr;                                         \
        const int phys_ = ((cc_) * 4 + lg) ^ (pix_ & 7);                       \
        const f16x8 bv_ = *(const f16x8*)                                      \
            ((const char*)&btile[MB][pix_][0] + phys_ * 16);                   \
        acc[0][nt] = __builtin_amdgcn_mfma_f32_16x16x32_f16(                   \
            AS, bv_, acc[0][nt], 0, 0, 0);                                     \
        acc[1][nt] = __builtin_amdgcn_mfma_f32_16x16x32_f16(                   \
            AT, bv_, acc[1][nt], 0, 0, 0);                                     \
    } }

#define G_ISSUE_8(t_)                                                          \
    G_ISSUE(t_, 0, qT0, qB0) G_ISSUE(t_, 1, qT1, qB1)                          \
    G_ISSUE(t_, 2, qT2, qB2) G_ISSUE(t_, 3, qT3, qB3)                          \
    G_ISSUE(t_, 4, qT4, qB4) G_ISSUE(t_, 5, qT5, qB5)                          \
    G_ISSUE(t_, 6, qT6, qB6) G_ISSUE(t_, 7, qT7, qB7)

    if constexpr (MODE == 0) {
        uint4 qT0, qB0, qT1, qB1, qT2, qB2, qT3, qB3;
        uint4 qT4, qB4, qT5, qB5, qT6, qB6, qT7, qB7;
        f16x8 aS0, aT0, aS1, aT1, aS2, aT2, aS3, aT3;

        // ---- prologue: A(0,0..1); G(0,0..7); stage(0); G(1,0..7) tail ----
        A_LOAD(0, 0, aS0, aT0)
        A_LOAD(0, 1, aS1, aT1)
        G_ISSUE_8(0)
        G_CONSUME(0, 0, qT0, qB0, 0)  G_ISSUE(0, 8, qT0, qB0)
        G_CONSUME(0, 1, qT1, qB1, 0)  G_ISSUE(0, 9, qT1, qB1)
        G_CONSUME(0, 2, qT2, qB2, 0)  G_ISSUE(0, 10, qT2, qB2)
        G_CONSUME(0, 3, qT3, qB3, 0)  G_ISSUE(0, 11, qT3, qB3)
        G_CONSUME(0, 4, qT4, qB4, 0)  G_ISSUE(0, 12, qT4, qB4)
        G_CONSUME(0, 5, qT5, qB5, 0)  G_ISSUE(0, 13, qT5, qB5)
        G_CONSUME(0, 6, qT6, qB6, 0)  G_ISSUE(0, 14, qT6, qB6)
        G_CONSUME(0, 7, qT7, qB7, 0)  G_ISSUE(0, 15, qT7, qB7)
        G_CONSUME(0, 8, qT0, qB0, 0)  G_CONSUME(0, 9, qT1, qB1, 0)
        G_CONSUME(0, 10, qT2, qB2, 0) G_CONSUME(0, 11, qT3, qB3, 0)
        G_CONSUME(0, 12, qT4, qB4, 0) G_CONSUME(0, 13, qT5, qB5, 0)
        G_CONSUME(0, 14, qT6, qB6, 0) G_CONSUME(0, 15, qT7, qB7, 0)
        G_ISSUE_8(1)
        asm volatile("s_waitcnt lgkmcnt(0)" ::: "memory");
        __builtin_amdgcn_s_barrier();

        for (int k = 0; k < K2_; ++k) {
            // ---- MFMA(k) + FIFO prefetch of A(k, 2..7), A(k+1, 0..1), G(k+1)
            const int mb = k & 1, sb = mb ^ 1;
            const int st = (k < K2_ - 1);     // staging this region?
            const int kn = st ? (k + 1) : k;  // safe index when !st

            A_LOAD(k, 2, aS2, aT2)
            if (st) { G_CONSUME(kn, 0, qT0, qB0, sb) G_ISSUE(kn, 8, qT0, qB0) }
            MFMA_CC(0, mb, aS0, aT0)
            A_LOAD(k, 3, aS3, aT3)
            if (st) { G_CONSUME(kn, 1, qT1, qB1, sb) G_ISSUE(kn, 9, qT1, qB1) }
            MFMA_CC(1, mb, aS1, aT1)
            A_LOAD(k, 4, aS0, aT0)
            if (st) { G_CONSUME(kn, 2, qT2, qB2, sb) G_ISSUE(kn, 10, qT2, qB2) }
            MFMA_CC(2, mb, aS2, aT2)
            A_LOAD(k, 5, aS1, aT1)
            if (st) { G_CONSUME(kn, 3, qT3, qB3, sb) G_ISSUE(kn, 11, qT3, qB3) }
            MFMA_CC(3, mb, aS3, aT3)
            A_LOAD(k, 6, aS2, aT2)
            if (st) { G_CONSUME(kn, 4, qT4, qB4, sb) G_ISSUE(kn, 12, qT4, qB4) }
            MFMA_CC(4, mb, aS0, aT0)
            A_LOAD(k, 7, aS3, aT3)
            if (st) { G_CONSUME(kn, 5, qT5, qB5, sb) G_ISSUE(kn, 13, qT5, qB5) }
            MFMA_CC(5, mb, aS1, aT1)
            if (st) {
                A_LOAD(kn, 0, aS0, aT0)
                A_LOAD(kn, 1, aS1, aT1)
                G_CONSUME(kn, 6, qT6, qB6, sb) G_ISSUE(kn, 14, qT6, qB6)
            }
            MFMA_CC(6, mb, aS2, aT2)
            if (st) { G_CONSUME(kn, 7, qT7, qB7, sb) G_ISSUE(kn, 15, qT7, qB7) }
            MFMA_CC(7, mb, aS3, aT3)
            if (st) {
                G_CONSUME(kn, 8, qT0, qB0, sb)  G_CONSUME(kn, 9, qT1, qB1, sb)
                G_CONSUME(kn, 10, qT2, qB2, sb) G_CONSUME(kn, 11, qT3, qB3, sb)
                G_CONSUME(kn, 12, qT4, qB4, sb) G_CONSUME(kn, 13, qT5, qB5, sb)
                G_CONSUME(kn, 14, qT6, qB6, sb) G_CONSUME(kn, 15, qT7, qB7, sb)
                if (k < K2_ - 2) { G_ISSUE_8(k + 2) }
            }
            asm volatile("s_waitcnt lgkmcnt(0)" ::: "memory");
            __builtin_amdgcn_s_barrier();
        }
    } else {
        // fallback: direct f32 corner loads (correctness only)
        for (int k = 0; k < K2_; ++k) {
#pragma unroll
            for (int j = 0; j < 16; ++j) {
                const int p_ = wv * 16 + j;
                const int qp = gaddr[k * 128 + p_];
                const uint2 wp_ = gw2[k * 128 + p_];
                const f16x2 wt_ = u2h(wp_.x), wb_ = u2h(wp_.y);
                const float w00 = (float)wt_.x, w01 = (float)wt_.y;
                const float w10 = (float)wb_.x, w11 = (float)wb_.y;
                float vv[4];
#pragma unroll
                for (int e2 = 0; e2 < 4; ++e2) {
                    const float* pl = x + ((size_t)(b * C_ + lane * 4 + e2)) * HW_;
                    vv[e2] = w00 * pl[qp] + w01 * pl[qp + 1]
                           + w10 * pl[qp + 64] + w11 * pl[qp + 65];
                }
                const unsigned pk0 = h2u(__builtin_amdgcn_cvt_pkrtz(vv[0], vv[1]));
                const unsigned pk1 = h2u(__builtin_amdgcn_cvt_pkrtz(vv[2], vv[3]));
                const int phys_ = (lane >> 1) ^ (p_ & 7);
                *(uint2*)((char*)&btile[0][p_][0] + phys_ * 16 + (lane & 1) * 8) =
                    make_uint2(pk0, pk1);
            }
            __syncthreads();
#pragma unroll
            for (int cc = 0; cc < 8; ++cc) {
                f16x8 a0, a1;
                A_LOAD(k, cc, a0, a1)
                MFMA_CC(cc, 0, a0, a1)
            }
            __syncthreads();
        }
    }

    // ---- epilogue: ReLU + store (C/D: col=lane&15 -> pixel, row=lg*4+r -> oc)
    const size_t ob = (size_t)b * C_ * HW_;
    const int hbase = ho2 * 2;
#pragma unroll
    for (int mt = 0; mt < 2; ++mt) {
        const int o0 = wv * 32 + mt * 16 + lg * 4;
#pragma unroll
        for (int nt = 0; nt < 8; ++nt) {
            const int pix = nt * 16 + lr;
            const int row = pix >> 6, wo = pix & 63;
#pragma unroll
            for (int r = 0; r < 4; ++r)
                out[ob + (size_t)(o0 + r) * HW_ + (size_t)(hbase + row) * W_ + wo] =
                    fmaxf(acc[mt][nt][r], 0.f);
        }
    }
#undef A_LOAD
#undef G_ISSUE
#undef G_CONSUME
#undef MFMA_CC
#undef G_ISSUE_8
}

extern "C" void kernel_launch(void* const* d_in, const int* in_sizes, int n_in,
                              void* d_out, int out_size, void* d_ws, size_t ws_size,
                              hipStream_t stream) {
    const float* x      = (const float*)d_in[0];
    const float* offset = (const float*)d_in[1];
    const float* weight = (const float*)d_in[2];
    float* out          = (float*)d_out;

    const size_t wA_bytes = (size_t)K2_ * C_ * C_ * 2;        // 1.18 MB
    const size_t xp_off   = wA_bytes;                         // 16B-aligned
    const size_t xp_bytes = (size_t)B_ * HW_ * NC4 * 16;      // 33.6 MB
    const size_t need     = xp_off + xp_bytes;                // ~34.7 MB

    unsigned short* wAp = (unsigned short*)d_ws;
    uint4*          xpp = (uint4*)((char*)d_ws + xp_off);

    pack_kernel<<<512 + 2304, 256, 0, stream>>>(x, weight, xpp, wAp);

    const size_t lds = 131072 + 9216 + 2304;   // 142,592 B
    if (ws_size >= need) {
        deform_main<0><<<256, 512, lds, stream>>>(x, xpp, offset, wAp, out);
    } else {
        deform_main<1><<<256, 512, lds, stream>>>(x, xpp, offset, wAp, out);
    }
}